// Round 13
// baseline (225.783 us; speedup 1.0000x reference)
//
#include <hip/hip_runtime.h>
#include <cstddef>

#define B_    16
#define SQ_   1024
#define SE_   1024
#define CIN_  256
#define DK_   64
#define H_    8
#define HD_   512
#define NROWS 16384
#define BN_EPS 1e-5f
#define NEG_SLOPE 0.01f

typedef __attribute__((ext_vector_type(8))) short bf16x8;
typedef __attribute__((ext_vector_type(4))) float f32x4;

// Raw barrier (no vmcnt drain) + manual LDS-write visibility wait.
#define BAR()        __builtin_amdgcn_s_barrier()
#define WAIT_LGKM0() asm volatile("s_waitcnt lgkmcnt(0)" ::: "memory")

__device__ __forceinline__ unsigned short f2bf(float f) {  // RNE
    unsigned int u = __float_as_uint(f);
    return (unsigned short)((u + 0x7FFFu + ((u >> 16) & 1u)) >> 16);
}

#if __has_builtin(__builtin_amdgcn_perm)
__device__ __forceinline__ unsigned int pack_trunc(float lo, float hi) {
    return __builtin_amdgcn_perm(__float_as_uint(hi), __float_as_uint(lo), 0x07060302u);
}
#else
__device__ __forceinline__ unsigned int pack_trunc(float lo, float hi) {
    return (__float_as_uint(lo) >> 16) | (__float_as_uint(hi) & 0xFFFF0000u);
}
#endif

#if __has_builtin(__builtin_amdgcn_exp2f)
#define EXP2F(x) __builtin_amdgcn_exp2f(x)
#else
#define EXP2F(x) exp2f(x)
#endif

__device__ __forceinline__ ushort4 pack4(f32x4 v) {
    ushort4 p;
    p.x = f2bf(v[0]); p.y = f2bf(v[1]);
    p.z = f2bf(v[2]); p.w = f2bf(v[3]);
    return p;
}

__device__ __forceinline__ bf16x8 cvt8(float4 f0, float4 f1) {  // trunc f32->bf16 x8
    uint4 pk;
    pk.x = pack_trunc(f0.x, f0.y);
    pk.y = pack_trunc(f0.z, f0.w);
    pk.z = pack_trunc(f1.x, f1.y);
    pk.w = pack_trunc(f1.z, f1.w);
    return *(bf16x8*)&pk;
}

// ---------------------------------------------------------------------------
// Weight casts (one dispatch). Wq gets 0.125*log2(e) folded in.
// Blocks 0..1 also zero the BN stats accumulators.
// ---------------------------------------------------------------------------
__global__ __launch_bounds__(256) void wcast(const float* __restrict__ Wq,
                                             const float* __restrict__ Wk,
                                             const float* __restrict__ Wv,
                                             const float* __restrict__ Wp,
                                             unsigned short* __restrict__ dWq,
                                             unsigned short* __restrict__ dWkv,
                                             unsigned short* __restrict__ dWp,
                                             float* __restrict__ stats) {
    if (blockIdx.x < 2) stats[blockIdx.x * 256 + threadIdx.x] = 0.f;
    int i = blockIdx.x * 256 + threadIdx.x;
    int which = i >> 15, off = i & 32767;
    const float* s; unsigned short* d; float sc = 1.0f;
    if (which == 0)      { s = Wq; d = dWq; sc = 0.18033688011112042f; }
    else if (which == 1) { s = Wk; d = dWkv; }
    else if (which == 2) { s = Wv; d = dWkv + 131072; }
    else                 { s = Wp; d = dWp; }
    float4 v = *(const float4*)(s + (size_t)off * 4);
    ushort4 pk;
    pk.x = f2bf(v.x * sc); pk.y = f2bf(v.y * sc);
    pk.z = f2bf(v.z * sc); pk.w = f2bf(v.w * sc);
    *(ushort4*)(d + (size_t)off * 4) = pk;
}

// ---------------------------------------------------------------------------
// Fused Q+KV projection GEMM v9: BARRIER-FREE k-loop (measured ~43 us).
// W tile (128x256 bf16 = 64 KB) staged in LDS ONCE (XOR-swizzled); each wave
// loads its OWN A rows directly from global f32, converts in-register,
// double-buffered. Zero barriers in the k-loop. XCD-aware decode.
// ---------------------------------------------------------------------------
__global__ __launch_bounds__(256) void gemm_qkv9(const float* __restrict__ qsrc,
                                                 const float* __restrict__ xsrc,
                                                 const unsigned short* __restrict__ Wqb,
                                                 const unsigned short* __restrict__ Wkvb,
                                                 unsigned short* __restrict__ qh,
                                                 unsigned short* __restrict__ khb,
                                                 unsigned short* __restrict__ vTb) {
    __shared__ __align__(16) unsigned short smem[32768];    // 64 KB
    unsigned short* Ws = smem;                              // W tile, swizzled
    unsigned short* Cs = smem;                              // epilogue reuse

    const int tid = threadIdx.x;
    const int w = tid >> 6, l = tid & 63, lq = l >> 4, lr = l & 15;

    // XCD-aware decode (bijective: 1536 = 8 * 192, 192 = 12 * 16)
    const int flat = blockIdx.x;
    const int xcd  = flat & 7;
    const int jj   = flat >> 3;          // 0..191
    const int bx   = jj % 12;
    const int by   = (jj / 12) + xcd * 16;

    const bool isQ = bx < 4;
    const bool isV = bx >= 8;
    const float* A = isQ ? qsrc : xsrc;
    const unsigned short* W = isQ ? Wqb : Wkvb;
    const int n0 = (isQ ? bx : bx - 4) * 128;
    const int m0 = by * 128;

    f32x4 acc[2][8] = {};
    float4 aA[8], aB[8];

    // per-wave A row bases (wave w owns rows w*32 .. w*32+31)
    const float* A0 = A + (size_t)(m0 + w * 32 + lr) * 256 + lq * 8;        // m=0
    const float* A1 = A + (size_t)(m0 + w * 32 + 16 + lr) * 256 + lq * 8;   // m=1

#define LOAD_A(buf, kstep) do {                                              \
        buf[0] = *(const float4*)(A0 + (kstep) * 64);                        \
        buf[1] = *(const float4*)(A0 + (kstep) * 64 + 4);                    \
        buf[2] = *(const float4*)(A0 + (kstep) * 64 + 32);                   \
        buf[3] = *(const float4*)(A0 + (kstep) * 64 + 36);                   \
        buf[4] = *(const float4*)(A1 + (kstep) * 64);                        \
        buf[5] = *(const float4*)(A1 + (kstep) * 64 + 4);                    \
        buf[6] = *(const float4*)(A1 + (kstep) * 64 + 32);                   \
        buf[7] = *(const float4*)(A1 + (kstep) * 64 + 36);                   \
    } while (0)

#define QKV_STEP(buf, kstep) do {                                            \
        _Pragma("unroll")                                                    \
        for (int ks = 0; ks < 2; ++ks) {                                     \
            bf16x8 a0 = cvt8(buf[ks * 2], buf[ks * 2 + 1]);                  \
            bf16x8 a1 = cvt8(buf[4 + ks * 2], buf[4 + ks * 2 + 1]);          \
            const int colu = (kstep) * 8 + ks * 4 + lq;                      \
            const int cswz = colu ^ (lr & 7);                                \
            if (!isV) {                                                      \
                _Pragma("unroll")                                            \
                for (int j = 0; j < 8; ++j) {                                \
                    bf16x8 bb = *(bf16x8*)&Ws[((j * 16 + lr) * 32 + cswz) * 8]; \
                    acc[0][j] = __builtin_amdgcn_mfma_f32_16x16x32_bf16(bb, a0, acc[0][j], 0, 0, 0); \
                    acc[1][j] = __builtin_amdgcn_mfma_f32_16x16x32_bf16(bb, a1, acc[1][j], 0, 0, 0); \
                }                                                            \
            } else {                                                         \
                _Pragma("unroll")                                            \
                for (int j = 0; j < 8; ++j) {                                \
                    bf16x8 bb = *(bf16x8*)&Ws[((j * 16 + lr) * 32 + cswz) * 8]; \
                    acc[0][j] = __builtin_amdgcn_mfma_f32_16x16x32_bf16(a0, bb, acc[0][j], 0, 0, 0); \
                    acc[1][j] = __builtin_amdgcn_mfma_f32_16x16x32_bf16(a1, bb, acc[1][j], 0, 0, 0); \
                }                                                            \
            }                                                                \
        }                                                                    \
    } while (0)

    // step-0 A loads overlap the W staging latency
    LOAD_A(aA, 0);

    // ---- stage W once: 128 rows x 32 16B-units, swizzled colu^(row&7) ----
    #pragma unroll
    for (int i = 0; i < 16; ++i) {
        int u = tid + i * 256;                 // 0..4095
        int row = u >> 5, colu = u & 31;
        uint4 v = *(const uint4*)(W + (size_t)(n0 + row) * 256 + colu * 8);
        *(uint4*)&Ws[(row * 32 + (colu ^ (row & 7))) * 8] = v;
    }
    __syncthreads();   // once per block; no pipelined loads to protect yet

    LOAD_A(aB, 1);
    QKV_STEP(aA, 0);
    LOAD_A(aA, 2);
    QKV_STEP(aB, 1);
    LOAD_A(aB, 3);
    QKV_STEP(aA, 2);
    QKV_STEP(aB, 3);

#undef LOAD_A
#undef QKV_STEP

    // ---- Epilogue: LDS staging, then full-line coalesced stores ----
    __syncthreads();
    const int c16 = tid & 15;
    const int rb  = tid >> 4;
    if (!isV) {
        #pragma unroll
        for (int mf = 0; mf < 2; ++mf)
            #pragma unroll
            for (int j = 0; j < 8; ++j)
                *(ushort4*)&Cs[(w * 32 + mf * 16 + lr) * 144 + j * 16 + lq * 4] =
                    pack4(acc[mf][j]);
        __syncthreads();
        unsigned short* C = isQ ? qh : khb;
        #pragma unroll
        for (int it = 0; it < 8; ++it) {
            int r = it * 16 + rb;
            *(uint4*)(C + (size_t)(m0 + r) * 512 + n0 + c16 * 8) =
                *(const uint4*)(Cs + r * 144 + c16 * 8);
        }
    } else {
        #pragma unroll
        for (int mf = 0; mf < 2; ++mf)
            #pragma unroll
            for (int j = 0; j < 8; ++j)
                *(ushort4*)&Cs[(j * 16 + lr) * 144 + w * 32 + mf * 16 + lq * 4] =
                    pack4(acc[mf][j]);
        __syncthreads();
        const int bb = m0 >> 10, t0 = m0 & 1023;
        #pragma unroll
        for (int it = 0; it < 8; ++it) {
            int el = it * 16 + rb;
            int colv = n0 - 512 + el;
            int hh = colv >> 6, e = colv & 63;
            *(uint4*)(vTb + (size_t)((bb * 8 + hh) * 64 + e) * 1024 + t0 + c16 * 8) =
                *(const uint4*)(Cs + el * 144 + c16 * 8);
        }
    }
}

// ---------------------------------------------------------------------------
// MFMA flash attention v14: v12 structure (256 q-rows/block, mm=0..3,
// grid 512, 108 VGPR, no spill) + K/V LDS DOUBLE-BUFFER with a single
// barrier per tile. Per iter ti: [write tile ti+1 -> idle buf (WAR-safe:
// that buf was last read in iter ti-1, before the barrier); issue tile
// ti+2 loads; compute tile ti; lgkm0+BAR]. Halves barrier crossings
// (32 -> 16) and hides the staging ds_writes under compute.
// R8-R10 lesson: the 128-row/4-block occupancy variant spills at the
// 64-VGPR allocation and loses; v12's 2-blocks/CU + deeper per-block
// pipeline is the better operating point.
// ---------------------------------------------------------------------------
__global__ __launch_bounds__(256) void attn_mfma14(const unsigned short* __restrict__ qh,
                                                   const unsigned short* __restrict__ kh,
                                                   const unsigned short* __restrict__ vT,
                                                   unsigned short* __restrict__ o) {
    __shared__ __align__(16) unsigned short Ks[2][64 * 64];   // dbuf 16 KB
    __shared__ __align__(16) unsigned short Vs[2][64 * 64];   // dbuf 16 KB
    __shared__ __align__(16) unsigned short Ps[4][64 * 40];   // per-wave 20 KB

    const int tid = threadIdx.x;
    const int w = tid >> 6, l = tid & 63, lq = l >> 4, lr = l & 15;

    // XCD-aware decode (bijective: 512 = 8 * 64, 64 = 4 * 16)
    const int flat = blockIdx.x;
    const int xcd  = flat & 7;
    const int jj   = flat >> 3;          // 0..63
    const int q0   = (jj & 3) * 256;
    const int hb   = (jj >> 2) + xcd * 16;   // 0..127
    const int h    = hb & 7;
    const int b    = hb >> 3;

    const int swz = (lr & 7) << 3;            // XOR swizzle for K/V reads (shorts)

    // Q fragments: lane lr holds row m = mm*16+lr, elems k = lq*8+j (+32)
    bf16x8 qf[4][2];
    #pragma unroll
    for (int mm = 0; mm < 4; ++mm) {
        const unsigned short* qr =
            qh + (size_t)(b * SQ_ + q0 + w * 64 + mm * 16 + lr) * HD_ + h * DK_;
        qf[mm][0] = *(const bf16x8*)(qr + lq * 8);
        qf[mm][1] = *(const bf16x8*)(qr + 32 + lq * 8);
    }

    const unsigned short* kb = kh + (size_t)(b * SE_) * HD_ + h * DK_;
    const unsigned short* vb = vT + (size_t)((b * 8 + h) * 64) * 1024;

    const int se = tid >> 3;                  // 0..31
    const int sc = (tid & 7) * 8;
    const int sswz = (se & 7) << 3;           // staging-write swizzle (rr&7 == se&7)

    float l_i[4] = {};                        // per-lane partial row-sum
    f32x4 oacc[4][4] = {};                    // [mm][e-strip j]; D[e][m]
    unsigned short* Pw = Ps[w];

    // ---- prologue: tile0 -> regs -> buf0; issue tile1 loads ----
    uint4 kR[2], vR[2];
    #pragma unroll
    for (int ps = 0; ps < 2; ++ps) {
        int rr = se + ps * 32;
        kR[ps] = *(const uint4*)(kb + (size_t)rr * HD_ + sc);
        vR[ps] = *(const uint4*)(vb + (size_t)rr * 1024 + sc);
    }
    #pragma unroll
    for (int ps = 0; ps < 2; ++ps) {
        int rr = se + ps * 32;
        int ad = ((rr * 64 + sc) ^ sswz);
        *(uint4*)&Ks[0][ad] = kR[ps];
        *(uint4*)&Vs[0][ad] = vR[ps];
    }
    #pragma unroll
    for (int ps = 0; ps < 2; ++ps) {
        int rr = se + ps * 32;
        kR[ps] = *(const uint4*)(kb + (size_t)(64 + rr) * HD_ + sc);
        vR[ps] = *(const uint4*)(vb + (size_t)rr * 1024 + 64 + sc);
    }
    WAIT_LGKM0();
    BAR();

    for (int ti = 0; ti < 16; ++ti) {
        unsigned short* Kc = Ks[ti & 1];
        unsigned short* Vc = Vs[ti & 1];
        // write tile ti+1 into the idle buffer; issue tile ti+2 loads
        if (ti + 1 < 16) {
            unsigned short* Kn = Ks[(ti + 1) & 1];
            unsigned short* Vn = Vs[(ti + 1) & 1];
            #pragma unroll
            for (int ps = 0; ps < 2; ++ps) {
                int rr = se + ps * 32;
                int ad = ((rr * 64 + sc) ^ sswz);
                *(uint4*)&Kn[ad] = kR[ps];
                *(uint4*)&Vn[ad] = vR[ps];
            }
            if (ti + 2 < 16) {
                int t2 = (ti + 2) * 64;
                #pragma unroll
                for (int ps = 0; ps < 2; ++ps) {
                    int rr = se + ps * 32;
                    kR[ps] = *(const uint4*)(kb + (size_t)(t2 + rr) * HD_ + sc);
                    vR[ps] = *(const uint4*)(vb + (size_t)rr * 1024 + t2 + sc);
                }
            }
        }

        // ---- QK^T half 0: keys 0..31 of tile ----
        f32x4 s0[2][4] = {};
        __builtin_amdgcn_s_setprio(1);
        #pragma unroll
        for (int ks = 0; ks < 2; ++ks)
            #pragma unroll
            for (int tt = 0; tt < 2; ++tt) {
                bf16x8 kf = *(bf16x8*)&Kc[((tt * 16 + lr) * 64 + ks * 32 + lq * 8) ^ swz];
                #pragma unroll
                for (int mm = 0; mm < 4; ++mm)
                    s0[tt][mm] = __builtin_amdgcn_mfma_f32_16x16x32_bf16(kf, qf[mm][ks], s0[tt][mm], 0, 0, 0);
            }
        __builtin_amdgcn_s_setprio(0);

        // exp0 + P0 write (t-local cols 0..31)
        #pragma unroll
        for (int mm = 0; mm < 4; ++mm)
            #pragma unroll
            for (int tt = 0; tt < 2; ++tt) {
                float e0 = EXP2F(s0[tt][mm][0]);
                float e1 = EXP2F(s0[tt][mm][1]);
                float e2 = EXP2F(s0[tt][mm][2]);
                float e3 = EXP2F(s0[tt][mm][3]);
                l_i[mm] += (e0 + e1) + (e2 + e3);
                uint2 pk;
                pk.x = pack_trunc(e0, e1);
                pk.y = pack_trunc(e2, e3);
                *(uint2*)&Pw[(mm * 16 + lr) * 40 + tt * 16 + lq * 4] = pk;
            }

        // ---- QK^T half 1: keys 32..63 (overlaps P0 write latency) ----
        f32x4 s1[2][4] = {};
        __builtin_amdgcn_s_setprio(1);
        #pragma unroll
        for (int ks = 0; ks < 2; ++ks)
            #pragma unroll
            for (int tt = 0; tt < 2; ++tt) {
                bf16x8 kf = *(bf16x8*)&Kc[(((tt + 2) * 16 + lr) * 64 + ks * 32 + lq * 8) ^ swz];
                #pragma unroll
                for (int mm = 0; mm < 4; ++mm)
                    s1[tt][mm] = __builtin_amdgcn_mfma_f32_16x16x32_bf16(kf, qf[mm][ks], s1[tt][mm], 0, 0, 0);
            }
        __builtin_amdgcn_s_setprio(0);

        asm volatile("s_waitcnt lgkmcnt(0)" ::: "memory");   // P0 writes done

        // ---- PV half 0: V cols 0..31 (MFMAs overlap exp1 below) ----
        __builtin_amdgcn_s_setprio(1);
        {
            bf16x8 pf[4];
            #pragma unroll
            for (int mm = 0; mm < 4; ++mm)
                pf[mm] = *(bf16x8*)&Pw[(mm * 16 + lr) * 40 + lq * 8];
            #pragma unroll
            for (int j = 0; j < 4; ++j) {
                bf16x8 vf = *(bf16x8*)&Vc[((j * 16 + lr) * 64 + lq * 8) ^ swz];
                #pragma unroll
                for (int mm = 0; mm < 4; ++mm)
                    oacc[mm][j] = __builtin_amdgcn_mfma_f32_16x16x32_bf16(vf, pf[mm], oacc[mm][j], 0, 0, 0);
            }
        }
        __builtin_amdgcn_s_setprio(0);

        // exp1 + P1 write (reuses P slots; WAR-safe: PV(h0) reads issued first)
        #pragma unroll
        for (int mm = 0; mm < 4; ++mm)
            #pragma unroll
            for (int tt = 0; tt < 2; ++tt) {
                float e0 = EXP2F(s1[tt][mm][0]);
                float e1 = EXP2F(s1[tt][mm][1]);
                float e2 = EXP2F(s1[tt][mm][2]);
                float e3 = EXP2F(s1[tt][mm][3]);
                l_i[mm] += (e0 + e1) + (e2 + e3);
                uint2 pk;
                pk.x = pack_trunc(e0, e1);
                pk.y = pack_trunc(e2, e3);
                *(uint2*)&Pw[(mm * 16 + lr) * 40 + tt * 16 + lq * 4] = pk;
            }

        asm volatile("s_waitcnt lgkmcnt(0)" ::: "memory");   // P1 writes done

        // ---- PV half 1: V cols 32..63 ----
        __builtin_amdgcn_s_setprio(1);
        {
            bf16x8 pf[4];
            #pragma unroll
            for (int mm = 0; mm < 4; ++mm)
                pf[mm] = *(bf16x8*)&Pw[(mm * 16 + lr) * 40 + lq * 8];
            #pragma unroll
            for (int j = 0; j < 4; ++j) {
                bf16x8 vf = *(bf16x8*)&Vc[((j * 16 + lr) * 64 + 32 + lq * 8) ^ swz];
                #pragma unroll
                for (int mm = 0; mm < 4; ++mm)
                    oacc[mm][j] = __builtin_amdgcn_mfma_f32_16x16x32_bf16(vf, pf[mm], oacc[mm][j], 0, 0, 0);
            }
        }
        __builtin_amdgcn_s_setprio(0);

        // single per-tile sync: my dbuf writes + P traffic committed
        if (ti + 1 < 16) {
            WAIT_LGKM0();
            BAR();
        }
    }

    float inv[4];
    #pragma unroll
    for (int mm = 0; mm < 4; ++mm) {
        float t = l_i[mm];
        t += __shfl_xor(t, 16);
        t += __shfl_xor(t, 32);
        inv[mm] = 1.0f / t;
    }

    // o store: D row = e_local = lq*4+r (4 consecutive e), col = m = lr.
    #pragma unroll
    for (int mm = 0; mm < 4; ++mm)
        #pragma unroll
        for (int j = 0; j < 4; ++j) {
            f32x4 v = oacc[mm][j];
            v[0] *= inv[mm]; v[1] *= inv[mm]; v[2] *= inv[mm]; v[3] *= inv[mm];
            *(ushort4*)&o[(size_t)(b * SQ_ + q0 + w * 64 + mm * 16 + lr) * HD_ +
                          h * DK_ + j * 16 + lq * 4] = pack4(v);
        }
}

// ---------------------------------------------------------------------------
// Output projection v3: BARRIER-FREE k-loop (gemm_qkv9 pattern, which
// measured -24 us on the same transformation). Wp tile 64x512 bf16 = 64 KB
// staged in LDS once (XOR-swizzled cu^(row&7)); each wave loads its OWN
// A rows (already bf16) directly from global, double-buffered over 8
// k-steps. Zero k-loop barriers. Fused BN partials unchanged.
// ---------------------------------------------------------------------------
__global__ __launch_bounds__(256) void gemm_out3(const unsigned short* __restrict__ A,
                                                 const unsigned short* __restrict__ W,
                                                 float* __restrict__ C,
                                                 float* __restrict__ gsum,
                                                 float* __restrict__ gsumsq) {
    __shared__ __align__(16) unsigned short Ws[32768];   // 64 KB: 64 rows x 64 cu
    const int tid = threadIdx.x;
    const int w = tid >> 6, l = tid & 63, lq = l >> 4, lr = l & 15;
    const int n0 = blockIdx.x * 64, m0 = blockIdx.y * 128;
    const int K = 512;

    f32x4 acc[2][4] = {};
    uint4 aA[4], aB[4];

    const unsigned short* A0 = A + (size_t)(m0 + w * 32 + lr) * K + lq * 8;
    const unsigned short* A1 = A + (size_t)(m0 + w * 32 + 16 + lr) * K + lq * 8;

#define LOADO(buf, kstep) do {                                               \
        buf[0] = *(const uint4*)(A0 + (kstep) * 64);                         \
        buf[1] = *(const uint4*)(A0 + (kstep) * 64 + 32);                    \
        buf[2] = *(const uint4*)(A1 + (kstep) * 64);                         \
        buf[3] = *(const uint4*)(A1 + (kstep) * 64 + 32);                    \
    } while (0)

#define OSTEP(buf, kstep) do {                                               \
        _Pragma("unroll")                                                    \
        for (int ks = 0; ks < 2; ++ks) {                                     \
            bf16x8 a0 = *(bf16x8*)&buf[ks];                                  \
            bf16x8 a1 = *(bf16x8*)&buf[2 + ks];                              \
            const int cu = (kstep) * 8 + ks * 4 + lq;                        \
            const int cswz = cu ^ (lr & 7);                                  \
            _Pragma("unroll")                                                \
            for (int j = 0; j < 4; ++j) {                                    \
                bf16x8 bb = *(bf16x8*)&Ws[((j * 16 + lr) * 64 + cswz) * 8];  \
                acc[0][j] = __builtin_amdgcn_mfma_f32_16x16x32_bf16(a0, bb, acc[0][j], 0, 0, 0); \
                acc[1][j] = __builtin_amdgcn_mfma_f32_16x16x32_bf16(a1, bb, acc[1][j], 0, 0, 0); \
            }                                                                \
        }                                                                    \
    } while (0)

    LOADO(aA, 0);

    // stage Wp rows n0..n0+63 once: 64 rows x 64 16B-units, swizzled
    #pragma unroll
    for (int i = 0; i < 16; ++i) {
        int u = tid + i * 256;                 // 0..4095
        int row = u >> 6, cu = u & 63;
        uint4 v = *(const uint4*)(W + (size_t)(n0 + row) * 512 + cu * 8);
        *(uint4*)&Ws[(row * 64 + (cu ^ (row & 7))) * 8] = v;
    }
    __syncthreads();

    LOADO(aB, 1); OSTEP(aA, 0);
    LOADO(aA, 2); OSTEP(aB, 1);
    LOADO(aB, 3); OSTEP(aA, 2);
    LOADO(aA, 4); OSTEP(aB, 3);
    LOADO(aB, 5); OSTEP(aA, 4);
    LOADO(aA, 6); OSTEP(aB, 5);
    LOADO(aB, 7); OSTEP(aA, 6);
    OSTEP(aB, 7);

#undef LOADO
#undef OSTEP

    float cs[4] = {}, cq[4] = {};
    #pragma unroll
    for (int m = 0; m < 2; ++m)
        #pragma unroll
        for (int j = 0; j < 4; ++j)
            #pragma unroll
            for (int r = 0; r < 4; ++r) {
                float v = acc[m][j][r];
                C[(size_t)(m0 + w * 32 + m * 16 + lq * 4 + r) * 256 + n0 + j * 16 + lr] = v;
                cs[j] += v;
                cq[j] += v * v;
            }
    #pragma unroll
    for (int j = 0; j < 4; ++j) {
        cs[j] += __shfl_xor(cs[j], 16); cs[j] += __shfl_xor(cs[j], 32);
        cq[j] += __shfl_xor(cq[j], 16); cq[j] += __shfl_xor(cq[j], 32);
    }
    __syncthreads();
    float* red = (float*)Ws;
    if (lq == 0) {
        #pragma unroll
        for (int j = 0; j < 4; ++j) {
            red[w * 128 + j * 16 + lr]      = cs[j];
            red[w * 128 + 64 + j * 16 + lr] = cq[j];
        }
    }
    __syncthreads();
    if (tid < 128) {
        int col = tid & 63, stat = tid >> 6;
        float t = red[stat * 64 + col] + red[128 + stat * 64 + col] +
                  red[256 + stat * 64 + col] + red[384 + stat * 64 + col];
        atomicAdd((stat ? gsumsq : gsum) + n0 + col, t);
    }
}

// ---------------------------------------------------------------------------
// Normalize + affine + LeakyReLU
// ---------------------------------------------------------------------------
__global__ __launch_bounds__(256) void bn_norm4(const float* __restrict__ p,
                                                const float* __restrict__ gsum,
                                                const float* __restrict__ gsumsq,
                                                const float* __restrict__ gamma,
                                                const float* __restrict__ beta,
                                                float* __restrict__ out) {
    int i = blockIdx.x * 256 + threadIdx.x;
    int c0 = (i * 4) & 255;
    const float invN = 1.0f / (float)NROWS;
    float4 pv = *(const float4*)(p + (size_t)i * 4);
    float vals[4] = {pv.x, pv.y, pv.z, pv.w};
    float res[4];
    #pragma unroll
    for (int k = 0; k < 4; ++k) {
        int c = c0 + k;
        float mean = gsum[c] * invN;
        float var  = gsumsq[c] * invN - mean * mean;
        float v = (vals[k] - mean) * rsqrtf(var + BN_EPS) * gamma[c] + beta[c];
        res[k] = v >= 0.f ? v : NEG_SLOPE * v;
    }
    float4 ov = {res[0], res[1], res[2], res[3]};
    *(float4*)(out + (size_t)i * 4) = ov;
}

// ---------------------------------------------------------------------------
// kernel_launch
// ---------------------------------------------------------------------------
extern "C" void kernel_launch(void* const* d_in, const int* in_sizes, int n_in,
                              void* d_out, int out_size, void* d_ws, size_t ws_size,
                              hipStream_t stream) {
    const float* x     = (const float*)d_in[0];
    const float* q     = (const float*)d_in[1];
    const float* Wq    = (const float*)d_in[2];
    const float* Wk    = (const float*)d_in[3];
    const float* Wv    = (const float*)d_in[4];
    const float* Wp    = (const float*)d_in[5];
    const float* gamma = (const float*)d_in[6];
    const float* beta  = (const float*)d_in[7];
    float* out = (float*)d_out;

    char* base = (char*)d_ws;
    unsigned short* Wqb  = (unsigned short*)(base + 0);          //  512x256 bf16
    unsigned short* Wkvb = (unsigned short*)(base + 262144);     // 1024x256 bf16
    unsigned short* Wpb  = (unsigned short*)(base + 786432);     //  256x512 bf16
    unsigned short* qh   = (unsigned short*)(base + 1048576);    // 16384x512 bf16
    unsigned short* khb  = (unsigned short*)(base + 17825792);   // 16384x512 bf16
    unsigned short* vTb  = (unsigned short*)(base + 34603008);   // [16,8,64,1024] bf16
    unsigned short* ob   = (unsigned short*)(base + 51380224);   // 16384x512 bf16
    float*          pbuf = (float*)        (base + 68157440);    // 16384x256 f32
    float*          stats= (float*)        (base + 84934656);    // 512 f32

    wcast<<<512, 256, 0, stream>>>(Wq, Wk, Wv, Wp, Wqb, Wkvb, Wpb, stats);

    gemm_qkv9<<<1536, 256, 0, stream>>>(q, x, Wqb, Wkvb, qh, khb, vTb);

    attn_mfma14<<<512, 256, 0, stream>>>(qh, khb, vTb, ob);

    gemm_out3<<<dim3(4, 128), 256, 0, stream>>>(ob, Wpb, pbuf, stats, stats + 256);

    bn_norm4<<<4096, 256, 0, stream>>>(pbuf, stats, stats + 256, gamma, beta, out);
}

// Round 14
// 201.550 us; speedup vs baseline: 1.1202x; 1.1202x over previous
//
#include <hip/hip_runtime.h>
#include <cstddef>

#define B_    16
#define SQ_   1024
#define SE_   1024
#define CIN_  256
#define DK_   64
#define H_    8
#define HD_   512
#define NROWS 16384
#define BN_EPS 1e-5f
#define NEG_SLOPE 0.01f

typedef __attribute__((ext_vector_type(8))) short bf16x8;
typedef __attribute__((ext_vector_type(4))) float f32x4;

// Raw barrier (no vmcnt drain) + manual LDS-write visibility wait.
#define BAR()        __builtin_amdgcn_s_barrier()
#define WAIT_LGKM0() asm volatile("s_waitcnt lgkmcnt(0)" ::: "memory")

__device__ __forceinline__ unsigned short f2bf(float f) {  // RNE
    unsigned int u = __float_as_uint(f);
    return (unsigned short)((u + 0x7FFFu + ((u >> 16) & 1u)) >> 16);
}

#if __has_builtin(__builtin_amdgcn_perm)
__device__ __forceinline__ unsigned int pack_trunc(float lo, float hi) {
    return __builtin_amdgcn_perm(__float_as_uint(hi), __float_as_uint(lo), 0x07060302u);
}
#else
__device__ __forceinline__ unsigned int pack_trunc(float lo, float hi) {
    return (__float_as_uint(lo) >> 16) | (__float_as_uint(hi) & 0xFFFF0000u);
}
#endif

#if __has_builtin(__builtin_amdgcn_exp2f)
#define EXP2F(x) __builtin_amdgcn_exp2f(x)
#else
#define EXP2F(x) exp2f(x)
#endif

__device__ __forceinline__ ushort4 pack4(f32x4 v) {
    ushort4 p;
    p.x = f2bf(v[0]); p.y = f2bf(v[1]);
    p.z = f2bf(v[2]); p.w = f2bf(v[3]);
    return p;
}

__device__ __forceinline__ bf16x8 cvt8(float4 f0, float4 f1) {  // trunc f32->bf16 x8
    uint4 pk;
    pk.x = pack_trunc(f0.x, f0.y);
    pk.y = pack_trunc(f0.z, f0.w);
    pk.z = pack_trunc(f1.x, f1.y);
    pk.w = pack_trunc(f1.z, f1.w);
    return *(bf16x8*)&pk;
}

// ---------------------------------------------------------------------------
// Weight casts (one dispatch). Wq gets 0.125*log2(e) folded in.
// Blocks 0..1 also zero the BN stats accumulators.
// ---------------------------------------------------------------------------
__global__ __launch_bounds__(256) void wcast(const float* __restrict__ Wq,
                                             const float* __restrict__ Wk,
                                             const float* __restrict__ Wv,
                                             const float* __restrict__ Wp,
                                             unsigned short* __restrict__ dWq,
                                             unsigned short* __restrict__ dWkv,
                                             unsigned short* __restrict__ dWp,
                                             float* __restrict__ stats) {
    if (blockIdx.x < 2) stats[blockIdx.x * 256 + threadIdx.x] = 0.f;
    int i = blockIdx.x * 256 + threadIdx.x;
    int which = i >> 15, off = i & 32767;
    const float* s; unsigned short* d; float sc = 1.0f;
    if (which == 0)      { s = Wq; d = dWq; sc = 0.18033688011112042f; }
    else if (which == 1) { s = Wk; d = dWkv; }
    else if (which == 2) { s = Wv; d = dWkv + 131072; }
    else                 { s = Wp; d = dWp; }
    float4 v = *(const float4*)(s + (size_t)off * 4);
    ushort4 pk;
    pk.x = f2bf(v.x * sc); pk.y = f2bf(v.y * sc);
    pk.z = f2bf(v.z * sc); pk.w = f2bf(v.w * sc);
    *(ushort4*)(d + (size_t)off * 4) = pk;
}

// ---------------------------------------------------------------------------
// Fused Q+KV projection GEMM v9: BARRIER-FREE k-loop.
// W tile (128x256 bf16 = 64 KB) staged in LDS ONCE (XOR-swizzled); each wave
// loads its OWN A rows directly from global f32, converts in-register,
// double-buffered. Zero barriers in the k-loop. XCD-aware decode.
// ---------------------------------------------------------------------------
__global__ __launch_bounds__(256) void gemm_qkv9(const float* __restrict__ qsrc,
                                                 const float* __restrict__ xsrc,
                                                 const unsigned short* __restrict__ Wqb,
                                                 const unsigned short* __restrict__ Wkvb,
                                                 unsigned short* __restrict__ qh,
                                                 unsigned short* __restrict__ khb,
                                                 unsigned short* __restrict__ vTb) {
    __shared__ __align__(16) unsigned short smem[32768];    // 64 KB
    unsigned short* Ws = smem;                              // W tile, swizzled
    unsigned short* Cs = smem;                              // epilogue reuse

    const int tid = threadIdx.x;
    const int w = tid >> 6, l = tid & 63, lq = l >> 4, lr = l & 15;

    // XCD-aware decode (bijective: 1536 = 8 * 192, 192 = 12 * 16)
    const int flat = blockIdx.x;
    const int xcd  = flat & 7;
    const int jj   = flat >> 3;          // 0..191
    const int bx   = jj % 12;
    const int by   = (jj / 12) + xcd * 16;

    const bool isQ = bx < 4;
    const bool isV = bx >= 8;
    const float* A = isQ ? qsrc : xsrc;
    const unsigned short* W = isQ ? Wqb : Wkvb;
    const int n0 = (isQ ? bx : bx - 4) * 128;
    const int m0 = by * 128;

    f32x4 acc[2][8] = {};
    float4 aA[8], aB[8];

    // per-wave A row bases (wave w owns rows w*32 .. w*32+31)
    const float* A0 = A + (size_t)(m0 + w * 32 + lr) * 256 + lq * 8;        // m=0
    const float* A1 = A + (size_t)(m0 + w * 32 + 16 + lr) * 256 + lq * 8;   // m=1

#define LOAD_A(buf, kstep) do {                                              \
        buf[0] = *(const float4*)(A0 + (kstep) * 64);                        \
        buf[1] = *(const float4*)(A0 + (kstep) * 64 + 4);                    \
        buf[2] = *(const float4*)(A0 + (kstep) * 64 + 32);                   \
        buf[3] = *(const float4*)(A0 + (kstep) * 64 + 36);                   \
        buf[4] = *(const float4*)(A1 + (kstep) * 64);                        \
        buf[5] = *(const float4*)(A1 + (kstep) * 64 + 4);                    \
        buf[6] = *(const float4*)(A1 + (kstep) * 64 + 32);                   \
        buf[7] = *(const float4*)(A1 + (kstep) * 64 + 36);                   \
    } while (0)

#define QKV_STEP(buf, kstep) do {                                            \
        _Pragma("unroll")                                                    \
        for (int ks = 0; ks < 2; ++ks) {                                     \
            bf16x8 a0 = cvt8(buf[ks * 2], buf[ks * 2 + 1]);                  \
            bf16x8 a1 = cvt8(buf[4 + ks * 2], buf[4 + ks * 2 + 1]);          \
            const int colu = (kstep) * 8 + ks * 4 + lq;                      \
            const int cswz = colu ^ (lr & 7);                                \
            if (!isV) {                                                      \
                _Pragma("unroll")                                            \
                for (int j = 0; j < 8; ++j) {                                \
                    bf16x8 bb = *(bf16x8*)&Ws[((j * 16 + lr) * 32 + cswz) * 8]; \
                    acc[0][j] = __builtin_amdgcn_mfma_f32_16x16x32_bf16(bb, a0, acc[0][j], 0, 0, 0); \
                    acc[1][j] = __builtin_amdgcn_mfma_f32_16x16x32_bf16(bb, a1, acc[1][j], 0, 0, 0); \
                }                                                            \
            } else {                                                         \
                _Pragma("unroll")                                            \
                for (int j = 0; j < 8; ++j) {                                \
                    bf16x8 bb = *(bf16x8*)&Ws[((j * 16 + lr) * 32 + cswz) * 8]; \
                    acc[0][j] = __builtin_amdgcn_mfma_f32_16x16x32_bf16(a0, bb, acc[0][j], 0, 0, 0); \
                    acc[1][j] = __builtin_amdgcn_mfma_f32_16x16x32_bf16(a1, bb, acc[1][j], 0, 0, 0); \
                }                                                            \
            }                                                                \
        }                                                                    \
    } while (0)

    // step-0 A loads overlap the W staging latency
    LOAD_A(aA, 0);

    // ---- stage W once: 128 rows x 32 16B-units, swizzled colu^(row&7) ----
    #pragma unroll
    for (int i = 0; i < 16; ++i) {
        int u = tid + i * 256;                 // 0..4095
        int row = u >> 5, colu = u & 31;
        uint4 v = *(const uint4*)(W + (size_t)(n0 + row) * 256 + colu * 8);
        *(uint4*)&Ws[(row * 32 + (colu ^ (row & 7))) * 8] = v;
    }
    __syncthreads();   // once per block; no pipelined loads to protect yet

    LOAD_A(aB, 1);
    QKV_STEP(aA, 0);
    LOAD_A(aA, 2);
    QKV_STEP(aB, 1);
    LOAD_A(aB, 3);
    QKV_STEP(aA, 2);
    QKV_STEP(aB, 3);

#undef LOAD_A
#undef QKV_STEP

    // ---- Epilogue: LDS staging, then full-line coalesced stores ----
    __syncthreads();
    const int c16 = tid & 15;
    const int rb  = tid >> 4;
    if (!isV) {
        #pragma unroll
        for (int mf = 0; mf < 2; ++mf)
            #pragma unroll
            for (int j = 0; j < 8; ++j)
                *(ushort4*)&Cs[(w * 32 + mf * 16 + lr) * 144 + j * 16 + lq * 4] =
                    pack4(acc[mf][j]);
        __syncthreads();
        unsigned short* C = isQ ? qh : khb;
        #pragma unroll
        for (int it = 0; it < 8; ++it) {
            int r = it * 16 + rb;
            *(uint4*)(C + (size_t)(m0 + r) * 512 + n0 + c16 * 8) =
                *(const uint4*)(Cs + r * 144 + c16 * 8);
        }
    } else {
        #pragma unroll
        for (int mf = 0; mf < 2; ++mf)
            #pragma unroll
            for (int j = 0; j < 8; ++j)
                *(ushort4*)&Cs[(j * 16 + lr) * 144 + w * 32 + mf * 16 + lq * 4] =
                    pack4(acc[mf][j]);
        __syncthreads();
        const int bb = m0 >> 10, t0 = m0 & 1023;
        #pragma unroll
        for (int it = 0; it < 8; ++it) {
            int el = it * 16 + rb;
            int colv = n0 - 512 + el;
            int hh = colv >> 6, e = colv & 63;
            *(uint4*)(vTb + (size_t)((bb * 8 + hh) * 64 + e) * 1024 + t0 + c16 * 8) =
                *(const uint4*)(Cs + el * 144 + c16 * 8);
        }
    }
}

// ---------------------------------------------------------------------------
// MFMA flash attention v12 (REVERT of v14): best measured attention
// (67.6 us, R6). v10 half-split pipeline + XCD decode + raw-barrier
// staging. R13 post-mortem: v14's dbuf raised VGPR 108->148 (wave-tier
// drop at 128) and occupancy 16.7->10.8 -> 90.8 us. v12's 2-barrier
// single-buffer loop at 108 VGPR is the proven operating point.
// ---------------------------------------------------------------------------
__global__ __launch_bounds__(256) void attn_mfma12(const unsigned short* __restrict__ qh,
                                                   const unsigned short* __restrict__ kh,
                                                   const unsigned short* __restrict__ vT,
                                                   unsigned short* __restrict__ o) {
    __shared__ __align__(16) unsigned short Ks[64 * 64];      // swizzled  8 KB
    __shared__ __align__(16) unsigned short Vs[64 * 64];      // swizzled  8 KB
    __shared__ __align__(16) unsigned short Ps[4][64 * 40];   // per-wave 20 KB

    const int tid = threadIdx.x;
    const int w = tid >> 6, l = tid & 63, lq = l >> 4, lr = l & 15;

    // XCD-aware decode (bijective: 512 = 8 * 64, 64 = 4 * 16)
    const int flat = blockIdx.x;
    const int xcd  = flat & 7;
    const int jj   = flat >> 3;          // 0..63
    const int q0   = (jj & 3) * 256;
    const int hb   = (jj >> 2) + xcd * 16;   // 0..127
    const int h    = hb & 7;
    const int b    = hb >> 3;

    const int swz = (lr & 7) << 3;            // XOR swizzle for K/V reads (shorts)

    // Q fragments: lane lr holds row m = mm*16+lr, elems k = lq*8+j (+32)
    bf16x8 qf[4][2];
    #pragma unroll
    for (int mm = 0; mm < 4; ++mm) {
        const unsigned short* qr =
            qh + (size_t)(b * SQ_ + q0 + w * 64 + mm * 16 + lr) * HD_ + h * DK_;
        qf[mm][0] = *(const bf16x8*)(qr + lq * 8);
        qf[mm][1] = *(const bf16x8*)(qr + 32 + lq * 8);
    }

    const unsigned short* kb = kh + (size_t)(b * SE_) * HD_ + h * DK_;
    const unsigned short* vb = vT + (size_t)((b * 8 + h) * 64) * 1024;

    const int se = tid >> 3;                  // 0..31
    const int sc = (tid & 7) * 8;
    const int sswz = (se & 7) << 3;           // staging-write swizzle (rr&7 == se&7)

    float l_i[4] = {};                        // per-lane partial row-sum
    f32x4 oacc[4][4] = {};                    // [mm][e-strip j]; D[e][m]
    unsigned short* Pw = Ps[w];

    // ---- prefetch K/V tile 0 into registers ----
    uint4 kR[2], vR[2];
    #pragma unroll
    for (int ps = 0; ps < 2; ++ps) {
        int rr = se + ps * 32;
        kR[ps] = *(const uint4*)(kb + (size_t)rr * HD_ + sc);
        vR[ps] = *(const uint4*)(vb + (size_t)rr * 1024 + sc);
    }

    for (int t0 = 0; t0 < SE_; t0 += 64) {
        BAR();   // raw: all waves done reading Ks/Vs of prev tile
        // write current tile (compiler inserts counted vmcnt for kR/vR deps)
        #pragma unroll
        for (int ps = 0; ps < 2; ++ps) {
            int rr = se + ps * 32;
            int ad = ((rr * 64 + sc) ^ sswz);
            *(uint4*)&Ks[ad] = kR[ps];
            *(uint4*)&Vs[ad] = vR[ps];
        }
        // issue next tile's loads; they stay in flight across the barrier
        if (t0 + 64 < SE_) {
            #pragma unroll
            for (int ps = 0; ps < 2; ++ps) {
                int rr = se + ps * 32;
                kR[ps] = *(const uint4*)(kb + (size_t)(t0 + 64 + rr) * HD_ + sc);
                vR[ps] = *(const uint4*)(vb + (size_t)rr * 1024 + t0 + 64 + sc);
            }
        }
        WAIT_LGKM0();            // my Ks/Vs writes committed
        BAR();                   // all writes visible; vmcnt NOT drained

        // ---- QK^T half 0: keys t0..t0+31 ----
        f32x4 s0[2][4] = {};
        __builtin_amdgcn_s_setprio(1);
        #pragma unroll
        for (int ks = 0; ks < 2; ++ks)
            #pragma unroll
            for (int tt = 0; tt < 2; ++tt) {
                bf16x8 kf = *(bf16x8*)&Ks[((tt * 16 + lr) * 64 + ks * 32 + lq * 8) ^ swz];
                #pragma unroll
                for (int mm = 0; mm < 4; ++mm)
                    s0[tt][mm] = __builtin_amdgcn_mfma_f32_16x16x32_bf16(kf, qf[mm][ks], s0[tt][mm], 0, 0, 0);
            }
        __builtin_amdgcn_s_setprio(0);

        // exp0 + P0 write (t-local cols 0..31)
        #pragma unroll
        for (int mm = 0; mm < 4; ++mm)
            #pragma unroll
            for (int tt = 0; tt < 2; ++tt) {
                float e0 = EXP2F(s0[tt][mm][0]);
                float e1 = EXP2F(s0[tt][mm][1]);
                float e2 = EXP2F(s0[tt][mm][2]);
                float e3 = EXP2F(s0[tt][mm][3]);
                l_i[mm] += (e0 + e1) + (e2 + e3);
                uint2 pk;
                pk.x = pack_trunc(e0, e1);
                pk.y = pack_trunc(e2, e3);
                *(uint2*)&Pw[(mm * 16 + lr) * 40 + tt * 16 + lq * 4] = pk;
            }

        // ---- QK^T half 1: keys t0+32..t0+63 (overlaps P0 write latency) ----
        f32x4 s1[2][4] = {};
        __builtin_amdgcn_s_setprio(1);
        #pragma unroll
        for (int ks = 0; ks < 2; ++ks)
            #pragma unroll
            for (int tt = 0; tt < 2; ++tt) {
                bf16x8 kf = *(bf16x8*)&Ks[(((tt + 2) * 16 + lr) * 64 + ks * 32 + lq * 8) ^ swz];
                #pragma unroll
                for (int mm = 0; mm < 4; ++mm)
                    s1[tt][mm] = __builtin_amdgcn_mfma_f32_16x16x32_bf16(kf, qf[mm][ks], s1[tt][mm], 0, 0, 0);
            }
        __builtin_amdgcn_s_setprio(0);

        asm volatile("s_waitcnt lgkmcnt(0)" ::: "memory");   // P0 writes done

        // ---- PV half 0: V cols t0..t0+31 (MFMAs overlap exp1 below) ----
        __builtin_amdgcn_s_setprio(1);
        {
            bf16x8 pf[4];
            #pragma unroll
            for (int mm = 0; mm < 4; ++mm)
                pf[mm] = *(bf16x8*)&Pw[(mm * 16 + lr) * 40 + lq * 8];
            #pragma unroll
            for (int j = 0; j < 4; ++j) {
                bf16x8 vf = *(bf16x8*)&Vs[((j * 16 + lr) * 64 + lq * 8) ^ swz];
                #pragma unroll
                for (int mm = 0; mm < 4; ++mm)
                    oacc[mm][j] = __builtin_amdgcn_mfma_f32_16x16x32_bf16(vf, pf[mm], oacc[mm][j], 0, 0, 0);
            }
        }
        __builtin_amdgcn_s_setprio(0);

        // exp1 + P1 write (reuses P slots; WAR-safe: PV(h0) reads issued first)
        #pragma unroll
        for (int mm = 0; mm < 4; ++mm)
            #pragma unroll
            for (int tt = 0; tt < 2; ++tt) {
                float e0 = EXP2F(s1[tt][mm][0]);
                float e1 = EXP2F(s1[tt][mm][1]);
                float e2 = EXP2F(s1[tt][mm][2]);
                float e3 = EXP2F(s1[tt][mm][3]);
                l_i[mm] += (e0 + e1) + (e2 + e3);
                uint2 pk;
                pk.x = pack_trunc(e0, e1);
                pk.y = pack_trunc(e2, e3);
                *(uint2*)&Pw[(mm * 16 + lr) * 40 + tt * 16 + lq * 4] = pk;
            }

        asm volatile("s_waitcnt lgkmcnt(0)" ::: "memory");   // P1 writes done

        // ---- PV half 1: V cols t0+32..t0+63 ----
        __builtin_amdgcn_s_setprio(1);
        {
            bf16x8 pf[4];
            #pragma unroll
            for (int mm = 0; mm < 4; ++mm)
                pf[mm] = *(bf16x8*)&Pw[(mm * 16 + lr) * 40 + lq * 8];
            #pragma unroll
            for (int j = 0; j < 4; ++j) {
                bf16x8 vf = *(bf16x8*)&Vs[((j * 16 + lr) * 64 + 32 + lq * 8) ^ swz];
                #pragma unroll
                for (int mm = 0; mm < 4; ++mm)
                    oacc[mm][j] = __builtin_amdgcn_mfma_f32_16x16x32_bf16(vf, pf[mm], oacc[mm][j], 0, 0, 0);
            }
        }
        __builtin_amdgcn_s_setprio(0);
    }

    float inv[4];
    #pragma unroll
    for (int mm = 0; mm < 4; ++mm) {
        float t = l_i[mm];
        t += __shfl_xor(t, 16);
        t += __shfl_xor(t, 32);
        inv[mm] = 1.0f / t;
    }

    // o store: D row = e_local = lq*4+r (4 consecutive e), col = m = lr.
    #pragma unroll
    for (int mm = 0; mm < 4; ++mm)
        #pragma unroll
        for (int j = 0; j < 4; ++j) {
            f32x4 v = oacc[mm][j];
            v[0] *= inv[mm]; v[1] *= inv[mm]; v[2] *= inv[mm]; v[3] *= inv[mm];
            *(ushort4*)&o[(size_t)(b * SQ_ + q0 + w * 64 + mm * 16 + lr) * HD_ +
                          h * DK_ + j * 16 + lq * 4] = pack4(v);
        }
}

// ---------------------------------------------------------------------------
// Output projection v3: BARRIER-FREE k-loop. Wp tile 64x512 bf16 = 64 KB
// staged in LDS once (XOR-swizzled cu^(row&7)); each wave loads its OWN
// A rows (already bf16) directly from global, double-buffered over 8
// k-steps. Zero k-loop barriers. Fused BN partials unchanged.
// ---------------------------------------------------------------------------
__global__ __launch_bounds__(256) void gemm_out3(const unsigned short* __restrict__ A,
                                                 const unsigned short* __restrict__ W,
                                                 float* __restrict__ C,
                                                 float* __restrict__ gsum,
                                                 float* __restrict__ gsumsq) {
    __shared__ __align__(16) unsigned short Ws[32768];   // 64 KB: 64 rows x 64 cu
    const int tid = threadIdx.x;
    const int w = tid >> 6, l = tid & 63, lq = l >> 4, lr = l & 15;
    const int n0 = blockIdx.x * 64, m0 = blockIdx.y * 128;
    const int K = 512;

    f32x4 acc[2][4] = {};
    uint4 aA[4], aB[4];

    const unsigned short* A0 = A + (size_t)(m0 + w * 32 + lr) * K + lq * 8;
    const unsigned short* A1 = A + (size_t)(m0 + w * 32 + 16 + lr) * K + lq * 8;

#define LOADO(buf, kstep) do {                                               \
        buf[0] = *(const uint4*)(A0 + (kstep) * 64);                         \
        buf[1] = *(const uint4*)(A0 + (kstep) * 64 + 32);                    \
        buf[2] = *(const uint4*)(A1 + (kstep) * 64);                         \
        buf[3] = *(const uint4*)(A1 + (kstep) * 64 + 32);                    \
    } while (0)

#define OSTEP(buf, kstep) do {                                               \
        _Pragma("unroll")                                                    \
        for (int ks = 0; ks < 2; ++ks) {                                     \
            bf16x8 a0 = *(bf16x8*)&buf[ks];                                  \
            bf16x8 a1 = *(bf16x8*)&buf[2 + ks];                              \
            const int cu = (kstep) * 8 + ks * 4 + lq;                        \
            const int cswz = cu ^ (lr & 7);                                  \
            _Pragma("unroll")                                                \
            for (int j = 0; j < 4; ++j) {                                    \
                bf16x8 bb = *(bf16x8*)&Ws[((j * 16 + lr) * 64 + cswz) * 8];  \
                acc[0][j] = __builtin_amdgcn_mfma_f32_16x16x32_bf16(a0, bb, acc[0][j], 0, 0, 0); \
                acc[1][j] = __builtin_amdgcn_mfma_f32_16x16x32_bf16(a1, bb, acc[1][j], 0, 0, 0); \
            }                                                                \
        }                                                                    \
    } while (0)

    LOADO(aA, 0);

    // stage Wp rows n0..n0+63 once: 64 rows x 64 16B-units, swizzled
    #pragma unroll
    for (int i = 0; i < 16; ++i) {
        int u = tid + i * 256;                 // 0..4095
        int row = u >> 6, cu = u & 63;
        uint4 v = *(const uint4*)(W + (size_t)(n0 + row) * 512 + cu * 8);
        *(uint4*)&Ws[(row * 64 + (cu ^ (row & 7))) * 8] = v;
    }
    __syncthreads();

    LOADO(aB, 1); OSTEP(aA, 0);
    LOADO(aA, 2); OSTEP(aB, 1);
    LOADO(aB, 3); OSTEP(aA, 2);
    LOADO(aA, 4); OSTEP(aB, 3);
    LOADO(aB, 5); OSTEP(aA, 4);
    LOADO(aA, 6); OSTEP(aB, 5);
    LOADO(aB, 7); OSTEP(aA, 6);
    OSTEP(aB, 7);

#undef LOADO
#undef OSTEP

    float cs[4] = {}, cq[4] = {};
    #pragma unroll
    for (int m = 0; m < 2; ++m)
        #pragma unroll
        for (int j = 0; j < 4; ++j)
            #pragma unroll
            for (int r = 0; r < 4; ++r) {
                float v = acc[m][j][r];
                C[(size_t)(m0 + w * 32 + m * 16 + lq * 4 + r) * 256 + n0 + j * 16 + lr] = v;
                cs[j] += v;
                cq[j] += v * v;
            }
    #pragma unroll
    for (int j = 0; j < 4; ++j) {
        cs[j] += __shfl_xor(cs[j], 16); cs[j] += __shfl_xor(cs[j], 32);
        cq[j] += __shfl_xor(cq[j], 16); cq[j] += __shfl_xor(cq[j], 32);
    }
    __syncthreads();
    float* red = (float*)Ws;
    if (lq == 0) {
        #pragma unroll
        for (int j = 0; j < 4; ++j) {
            red[w * 128 + j * 16 + lr]      = cs[j];
            red[w * 128 + 64 + j * 16 + lr] = cq[j];
        }
    }
    __syncthreads();
    if (tid < 128) {
        int col = tid & 63, stat = tid >> 6;
        float t = red[stat * 64 + col] + red[128 + stat * 64 + col] +
                  red[256 + stat * 64 + col] + red[384 + stat * 64 + col];
        atomicAdd((stat ? gsumsq : gsum) + n0 + col, t);
    }
}

// ---------------------------------------------------------------------------
// Normalize + affine + LeakyReLU
// ---------------------------------------------------------------------------
__global__ __launch_bounds__(256) void bn_norm4(const float* __restrict__ p,
                                                const float* __restrict__ gsum,
                                                const float* __restrict__ gsumsq,
                                                const float* __restrict__ gamma,
                                                const float* __restrict__ beta,
                                                float* __restrict__ out) {
    int i = blockIdx.x * 256 + threadIdx.x;
    int c0 = (i * 4) & 255;
    const float invN = 1.0f / (float)NROWS;
    float4 pv = *(const float4*)(p + (size_t)i * 4);
    float vals[4] = {pv.x, pv.y, pv.z, pv.w};
    float res[4];
    #pragma unroll
    for (int k = 0; k < 4; ++k) {
        int c = c0 + k;
        float mean = gsum[c] * invN;
        float var  = gsumsq[c] * invN - mean * mean;
        float v = (vals[k] - mean) * rsqrtf(var + BN_EPS) * gamma[c] + beta[c];
        res[k] = v >= 0.f ? v : NEG_SLOPE * v;
    }
    float4 ov = {res[0], res[1], res[2], res[3]};
    *(float4*)(out + (size_t)i * 4) = ov;
}

// ---------------------------------------------------------------------------
// kernel_launch
// ---------------------------------------------------------------------------
extern "C" void kernel_launch(void* const* d_in, const int* in_sizes, int n_in,
                              void* d_out, int out_size, void* d_ws, size_t ws_size,
                              hipStream_t stream) {
    const float* x     = (const float*)d_in[0];
    const float* q     = (const float*)d_in[1];
    const float* Wq    = (const float*)d_in[2];
    const float* Wk    = (const float*)d_in[3];
    const float* Wv    = (const float*)d_in[4];
    const float* Wp    = (const float*)d_in[5];
    const float* gamma = (const float*)d_in[6];
    const float* beta  = (const float*)d_in[7];
    float* out = (float*)d_out;

    char* base = (char*)d_ws;
    unsigned short* Wqb  = (unsigned short*)(base + 0);          //  512x256 bf16
    unsigned short* Wkvb = (unsigned short*)(base + 262144);     // 1024x256 bf16
    unsigned short* Wpb  = (unsigned short*)(base + 786432);     //  256x512 bf16
    unsigned short* qh   = (unsigned short*)(base + 1048576);    // 16384x512 bf16
    unsigned short* khb  = (unsigned short*)(base + 17825792);   // 16384x512 bf16
    unsigned short* vTb  = (unsigned short*)(base + 34603008);   // [16,8,64,1024] bf16
    unsigned short* ob   = (unsigned short*)(base + 51380224);   // 16384x512 bf16
    float*          pbuf = (float*)        (base + 68157440);    // 16384x256 f32
    float*          stats= (float*)        (base + 84934656);    // 512 f32

    wcast<<<512, 256, 0, stream>>>(Wq, Wk, Wv, Wp, Wqb, Wkvb, Wpb, stats);

    gemm_qkv9<<<1536, 256, 0, stream>>>(q, x, Wqb, Wkvb, qh, khb, vTb);

    attn_mfma12<<<512, 256, 0, stream>>>(qh, khb, vTb, ob);

    gemm_out3<<<dim3(4, 128), 256, 0, stream>>>(ob, Wpb, pbuf, stats, stats + 256);

    bn_norm4<<<4096, 256, 0, stream>>>(pbuf, stats, stats + 256, gamma, beta, out);
}